// Round 8
// baseline (487.238 us; speedup 1.0000x reference)
//
#include <hip/hip_runtime.h>
#include <hip/hip_bf16.h>
#include <cstdint>
#include <cstddef>

#define BB 256
#define NN 128
#define LL 2048
#define DD 64
#define KS 23
#define CPAD 12   // column pad in conv tile (band window requires 11..13)
#define EPSF 1e-6f

typedef __bf16 v8bf __attribute__((ext_vector_type(8)));
typedef float v4f __attribute__((ext_vector_type(4)));

__device__ __forceinline__ float bf2f(uint32_t u) {
  union { uint32_t i; float f; } c; c.i = u << 16; return c.f;
}
__device__ __forceinline__ uint16_t f2bf(float f) {
  union { float f; uint32_t i; } c; c.f = f;
  uint32_t i = c.i;
  return (uint16_t)((i + 0x7fffu + ((i >> 16) & 1u)) >> 16);
}
__device__ __forceinline__ v8bf cvt8(float4 f0, float4 f1) {
  v8bf r;
  r[0] = (__bf16)f0.x; r[1] = (__bf16)f0.y; r[2] = (__bf16)f0.z; r[3] = (__bf16)f0.w;
  r[4] = (__bf16)f1.x; r[5] = (__bf16)f1.y; r[6] = (__bf16)f1.z; r[7] = (__bf16)f1.w;
  return r;
}

// ----------------------------------------------------------- GNN body ------
// Runs as block x==0 of the conv0 dispatch (independent of conv0's data).
#define XSS 68    // xs row stride (words)
#define HTS3 136  // hsT row stride (halves)

__device__ void gnn_body(char* smem,
    const int* __restrict__ atoms, const float* __restrict__ atoms_mask,
    const float* __restrict__ adj, const float* __restrict__ emb_fp,
    const float* __restrict__ W_gnn, const float* __restrict__ b_gnn,
    const float* __restrict__ W_att, const float* __restrict__ b_att,
    float* __restrict__ compound, float* __restrict__ hvec_g)
{
  float*    xs     = (float*)smem;              // 128*68*4 = 34816
  uint16_t* hsT    = (uint16_t*)(smem + 34816); // 64*136*2 = 17408
  float*    mask_s = (float*)(smem + 52224);    // 512
  float*    psum   = (float*)(smem + 52736);    // 4*64*4 = 1024
  float*    cvec   = (float*)(smem + 53760);    // 256

  const int b = blockIdx.y;
  const int tid = threadIdx.x;
  const int lane = tid & 63;
  const int w = tid >> 6;
  const int m16 = lane & 15;
  const int s = lane >> 4;

  for (int idx = tid; idx < NN * 16; idx += 256) {
    int n = idx >> 4, c4 = idx & 15;
    int a = atoms[b * NN + n];
    float4 v = ((const float4*)(emb_fp + (size_t)a * DD))[c4];
    *(float4*)(xs + n * XSS + c4 * 4) = v;
  }
  if (tid < NN) mask_s[tid] = atoms_mask[b * NN + tid];
  __syncthreads();

  const int row0 = 32 * w;
  for (int layer = 0; layer < 3; ++layer) {
    v8bf Wf[2][4];
    float bias[4];
    const float* Wl = W_gnn + (size_t)layer * DD * DD;
    #pragma unroll
    for (int nt = 0; nt < 4; ++nt) {
      bias[nt] = b_gnn[layer * DD + nt * 16 + m16];
      #pragma unroll
      for (int kc = 0; kc < 2; ++kc) {
        const float* p = Wl + (size_t)(nt * 16 + m16) * DD + kc * 32 + s * 8;
        Wf[kc][nt] = cvt8(((const float4*)p)[0], ((const float4*)p)[1]);
      }
    }
    float4 araw[8][2];
    const float* adjw = adj + ((size_t)b * NN + row0) * NN;
    #pragma unroll
    for (int kc = 0; kc < 4; ++kc)
      #pragma unroll
      for (int mt = 0; mt < 2; ++mt) {
        const float* p = adjw + (size_t)(mt * 16 + m16) * NN + kc * 32 + s * 8;
        araw[kc * 2 + mt][0] = ((const float4*)p)[0];
        araw[kc * 2 + mt][1] = ((const float4*)p)[1];
      }

    v4f acc[2][4];
    #pragma unroll
    for (int mt = 0; mt < 2; ++mt)
      #pragma unroll
      for (int nt = 0; nt < 4; ++nt)
        acc[mt][nt] = (v4f){bias[nt], bias[nt], bias[nt], bias[nt]};
    #pragma unroll
    for (int kc = 0; kc < 2; ++kc) {
      v8bf Axs[2];
      #pragma unroll
      for (int mt = 0; mt < 2; ++mt) {
        const float* p = xs + (size_t)(row0 + mt * 16 + m16) * XSS + kc * 32 + s * 8;
        Axs[mt] = cvt8(((const float4*)p)[0], ((const float4*)p)[1]);
      }
      #pragma unroll
      for (int mt = 0; mt < 2; ++mt)
        #pragma unroll
        for (int nt = 0; nt < 4; ++nt)
          acc[mt][nt] = __builtin_amdgcn_mfma_f32_16x16x32_bf16(
              Axs[mt], Wf[kc][nt], acc[mt][nt], 0, 0, 0);
    }
    __syncthreads();
    #pragma unroll
    for (int mt = 0; mt < 2; ++mt)
      #pragma unroll
      for (int nt = 0; nt < 4; ++nt) {
        int e = nt * 16 + m16;
        int m = row0 + mt * 16 + s * 4;
        union { uint64_t u; __bf16 h[4]; } pk;
        #pragma unroll
        for (int r = 0; r < 4; ++r)
          pk.h[r] = (__bf16)fmaxf(acc[mt][nt][r], 0.f);
        *(uint64_t*)(hsT + (size_t)e * HTS3 + m) = pk.u;
      }
    __syncthreads();

    v4f acc2[2][4];
    #pragma unroll
    for (int mt = 0; mt < 2; ++mt)
      #pragma unroll
      for (int nt = 0; nt < 4; ++nt)
        #pragma unroll
        for (int r = 0; r < 4; ++r)
          acc2[mt][nt][r] = xs[(size_t)(row0 + mt * 16 + s * 4 + r) * XSS + nt * 16 + m16];
    #pragma unroll
    for (int kc = 0; kc < 4; ++kc) {
      v8bf Aa[2];
      #pragma unroll
      for (int mt = 0; mt < 2; ++mt)
        Aa[mt] = cvt8(araw[kc * 2 + mt][0], araw[kc * 2 + mt][1]);
      v8bf Bh[4];
      #pragma unroll
      for (int nt = 0; nt < 4; ++nt)
        Bh[nt] = *(const v8bf*)(hsT + (size_t)(nt * 16 + m16) * HTS3 + kc * 32 + s * 8);
      #pragma unroll
      for (int mt = 0; mt < 2; ++mt)
        #pragma unroll
        for (int nt = 0; nt < 4; ++nt)
          acc2[mt][nt] = __builtin_amdgcn_mfma_f32_16x16x32_bf16(
              Aa[mt], Bh[nt], acc2[mt][nt], 0, 0, 0);
    }
    #pragma unroll
    for (int mt = 0; mt < 2; ++mt)
      #pragma unroll
      for (int nt = 0; nt < 4; ++nt)
        #pragma unroll
        for (int r = 0; r < 4; ++r)
          xs[(size_t)(row0 + mt * 16 + s * 4 + r) * XSS + nt * 16 + m16] = acc2[mt][nt][r];
  }

  float pr = 0.f;
  for (int i = 0; i < 32; ++i) {
    int n = row0 + i;
    pr = fmaf(mask_s[n], xs[(size_t)n * XSS + lane], pr);
  }
  psum[w * 64 + lane] = pr;
  __syncthreads();
  if (tid < 64) {
    float ssum = psum[0 * 64 + tid] + psum[1 * 64 + tid]
               + psum[2 * 64 + tid] + psum[3 * 64 + tid];
    float den = 0.f;
    #pragma unroll 8
    for (int i = 0; i < NN; ++i) den += mask_s[i];
    float c = ssum / (den + EPSF);
    compound[b * DD + tid] = c;
    cvec[tid] = c;
  }
  __syncthreads();
  if (tid < 64) {
    float a = b_att[tid];
    const float* wr = W_att + (size_t)tid * DD;
    #pragma unroll
    for (int d4 = 0; d4 < 16; ++d4) {
      float4 w4 = ((const float4*)wr)[d4];
      float4 c4 = ((const float4*)cvec)[d4];
      a = fmaf(w4.x, c4.x, a); a = fmaf(w4.y, c4.y, a);
      a = fmaf(w4.z, c4.z, a); a = fmaf(w4.w, c4.w, a);
    }
    hvec_g[b * DD + tid] = fmaxf(a, 0.f);
  }
}

// -------------------------------------------- B-fragment table precompute --
__global__ __launch_bounds__(64) void bfrag_kernel(
    const float* __restrict__ conv_k, uint16_t* __restrict__ btab)
{
  const int layer = blockIdx.x;
  const int lane = threadIdx.x;
  const int s = lane >> 4, n = lane & 15;
  for (int kk = 0; kk < 30; ++kk) {
    int k8 = kk * 4 + s;
    int i = k8 / 5;
    int c8 = k8 - i * 5;
    #pragma unroll
    for (int j = 0; j < 8; ++j) {
      int c = c8 * 8 + j;
      int jj = c - n - 1;
      float v = (i < KS && jj >= 0 && jj < KS)
                    ? conv_k[layer * KS * KS + i * KS + jj] : 0.f;
      btab[(((size_t)layer * 30 + kk) * 64 + lane) * 8 + j] = f2bf(v);
    }
  }
}

// ------------------------------------------- conv layers 0,1 (+fused gnn) --
#define TW 88
#define TROWS 86

__global__ __launch_bounds__(256, 2) void conv01_kernel(
    const uint16_t* __restrict__ in, uint16_t* __restrict__ out,
    const uint16_t* __restrict__ btab, const float* __restrict__ conv_b,
    const int* __restrict__ amino, const float* __restrict__ emb_word,
    const int* __restrict__ atoms, const float* __restrict__ atoms_mask,
    const float* __restrict__ adj, const float* __restrict__ emb_fp,
    const float* __restrict__ W_gnn, const float* __restrict__ b_gnn,
    const float* __restrict__ W_att, const float* __restrict__ b_att,
    float* __restrict__ compound, float* __restrict__ hvec_g,
    int layer, int gmode)
{
  __shared__ __align__(16) char smem[54016];
  if (gmode && blockIdx.x == 0) {
    gnn_body(smem, atoms, atoms_mask, adj, emb_fp, W_gnn, b_gnn,
             W_att, b_att, compound, hvec_g);
    return;
  }
  uint16_t* tile = (uint16_t*)smem;
  const int tl = gmode ? (int)blockIdx.x - 1 : (int)blockIdx.x;
  const int tid = threadIdx.x;
  const int l0 = tl * 64;
  const int b  = blockIdx.y;
  const int lane = tid & 63;
  const int g = tid >> 6;

  v8bf bfr[30];
  const uint16_t* bt = btab + (size_t)layer * 30 * 512 + lane * 8;
  #pragma unroll
  for (int kk = 0; kk < 30; ++kk)
    bfr[kk] = *(const v8bf*)(bt + kk * 512);

  for (int i = tid; i < TROWS * 6; i += 256) {
    int r = i / 6, h = i - r * 6;
    int off = (h < 3) ? h * 4 : 76 + (h - 3) * 4;
    *(uint2*)(tile + r * TW + off) = make_uint2(0u, 0u);
  }
  const uint16_t* inb = in + (size_t)b * LL * DD;
  for (int idx = tid; idx < TROWS * 8; idx += 256) {
    int t = idx >> 3, c8 = idx & 7;
    int gl = l0 - 11 + t;
    uint16_t* dst = tile + t * TW + CPAD + c8 * 8;
    if (gl >= 0 && gl < LL) {
      if (gmode) {
        int a = amino[b * LL + gl];
        const float* src = emb_word + (size_t)a * DD + c8 * 8;
        float4 f0 = ((const float4*)src)[0];
        float4 f1 = ((const float4*)src)[1];
        union { uint2 u2[2]; uint16_t h[8]; } pk;
        pk.h[0] = f2bf(f0.x); pk.h[1] = f2bf(f0.y);
        pk.h[2] = f2bf(f0.z); pk.h[3] = f2bf(f0.w);
        pk.h[4] = f2bf(f1.x); pk.h[5] = f2bf(f1.y);
        pk.h[6] = f2bf(f1.z); pk.h[7] = f2bf(f1.w);
        *(uint2*)(dst)     = pk.u2[0];
        *(uint2*)(dst + 4) = pk.u2[1];
      } else {
        uint4 v = *(const uint4*)(inb + (size_t)gl * DD + c8 * 8);
        *(uint2*)(dst)     = make_uint2(v.x, v.y);
        *(uint2*)(dst + 4) = make_uint2(v.z, v.w);
      }
    } else {
      *(uint2*)(dst)     = make_uint2(0u, 0u);
      *(uint2*)(dst + 4) = make_uint2(0u, 0u);
    }
  }
  __syncthreads();

  const int s = lane >> 4;
  const int m16 = lane & 15;
  v4f acc[4];
  #pragma unroll
  for (int m = 0; m < 4; ++m) acc[m] = (v4f){0.f, 0.f, 0.f, 0.f};

  #pragma unroll
  for (int kk = 0; kk < 30; ++kk) {
    int k8 = kk * 4 + s;
    int i = k8 / 5;
    int c8 = k8 - i * 5;
    const uint16_t* ap = tile + (m16 + i) * TW + 16 * g + c8 * 8;
    v8bf a0 = *(const v8bf*)(ap);
    v8bf a1 = *(const v8bf*)(ap + 16 * TW);
    v8bf a2 = *(const v8bf*)(ap + 32 * TW);
    v8bf a3 = *(const v8bf*)(ap + 48 * TW);
    acc[0] = __builtin_amdgcn_mfma_f32_16x16x32_bf16(a0, bfr[kk], acc[0], 0, 0, 0);
    acc[1] = __builtin_amdgcn_mfma_f32_16x16x32_bf16(a1, bfr[kk], acc[1], 0, 0, 0);
    acc[2] = __builtin_amdgcn_mfma_f32_16x16x32_bf16(a2, bfr[kk], acc[2], 0, 0, 0);
    acc[3] = __builtin_amdgcn_mfma_f32_16x16x32_bf16(a3, bfr[kk], acc[3], 0, 0, 0);
  }

  const float bias = conv_b[layer];
  uint16_t* outb = out + ((size_t)b * LL + l0) * DD + 16 * g + m16;
  #pragma unroll
  for (int m = 0; m < 4; ++m) {
    #pragma unroll
    for (int r = 0; r < 4; ++r) {
      int row = m * 16 + s * 4 + r;
      outb[(size_t)row * DD] = f2bf(fmaxf(acc[m][r] + bias, 0.f));
    }
  }
}

// -------------------------------------- conv layer 2 + fused attention -----
// After the conv MFMAs: ps tile (bf16) round-trips through LDS (C->A layout),
// hs = relu(ps@W_att^T+b)*mask via 8 MFMAs/wave, tanh row-dot, per-wave
// protein partial written to a (b,tile,wave) slot. No ps_b global write.
#define T2S 68   // tile2 row stride in halves; odd rows shifted +4 for 16B...
                 // (A-frags read as 2x ds_read_b64, only 8B align needed)

__global__ __launch_bounds__(256, 2) void conv2attn_kernel(
    const uint16_t* __restrict__ in, const uint16_t* __restrict__ btab,
    const float* __restrict__ conv_b, const float* __restrict__ amino_mask,
    const float* __restrict__ hvec_g, const float* __restrict__ W_att,
    const float* __restrict__ b_att, float* __restrict__ pacc_g,
    float* __restrict__ msum_g)
{
  __shared__ __align__(16) char smem[33312];
  uint16_t* tile  = (uint16_t*)smem;            // 15136 B (tile2 aliases it)
  float*    ht    = (float*)(smem + 15136);     // 4 waves * 16*68 floats
  float*    wv_s  = (float*)(smem + 32544);     // 4*16
  float*    pm_s  = (float*)(smem + 32800);     // 64
  float*    hv_s  = (float*)(smem + 33056);     // 64

  const int layer = 2;
  const int tid = threadIdx.x;
  const int tl = blockIdx.x;
  const int l0 = tl * 64;
  const int b  = blockIdx.y;
  const int lane = tid & 63;
  const int g = tid >> 6;

  v8bf bfr[30];
  const uint16_t* bt = btab + (size_t)layer * 30 * 512 + lane * 8;
  #pragma unroll
  for (int kk = 0; kk < 30; ++kk)
    bfr[kk] = *(const v8bf*)(bt + kk * 512);

  for (int i = tid; i < TROWS * 6; i += 256) {
    int r = i / 6, h = i - r * 6;
    int off = (h < 3) ? h * 4 : 76 + (h - 3) * 4;
    *(uint2*)(tile + r * TW + off) = make_uint2(0u, 0u);
  }
  const uint16_t* inb = in + (size_t)b * LL * DD;
  for (int idx = tid; idx < TROWS * 8; idx += 256) {
    int t = idx >> 3, c8 = idx & 7;
    int gl = l0 - 11 + t;
    uint16_t* dst = tile + t * TW + CPAD + c8 * 8;
    if (gl >= 0 && gl < LL) {
      uint4 v = *(const uint4*)(inb + (size_t)gl * DD + c8 * 8);
      *(uint2*)(dst)     = make_uint2(v.x, v.y);
      *(uint2*)(dst + 4) = make_uint2(v.z, v.w);
    } else {
      *(uint2*)(dst)     = make_uint2(0u, 0u);
      *(uint2*)(dst + 4) = make_uint2(0u, 0u);
    }
  }
  if (tid < 64) {
    pm_s[tid] = amino_mask[(size_t)b * LL + l0 + tid];
    hv_s[tid] = hvec_g[b * DD + tid];
  }
  __syncthreads();

  const int s = lane >> 4;
  const int m16 = lane & 15;
  v4f acc[4];
  #pragma unroll
  for (int m = 0; m < 4; ++m) acc[m] = (v4f){0.f, 0.f, 0.f, 0.f};

  #pragma unroll
  for (int kk = 0; kk < 30; ++kk) {
    int k8 = kk * 4 + s;
    int i = k8 / 5;
    int c8 = k8 - i * 5;
    const uint16_t* ap = tile + (m16 + i) * TW + 16 * g + c8 * 8;
    v8bf a0 = *(const v8bf*)(ap);
    v8bf a1 = *(const v8bf*)(ap + 16 * TW);
    v8bf a2 = *(const v8bf*)(ap + 32 * TW);
    v8bf a3 = *(const v8bf*)(ap + 48 * TW);
    acc[0] = __builtin_amdgcn_mfma_f32_16x16x32_bf16(a0, bfr[kk], acc[0], 0, 0, 0);
    acc[1] = __builtin_amdgcn_mfma_f32_16x16x32_bf16(a1, bfr[kk], acc[1], 0, 0, 0);
    acc[2] = __builtin_amdgcn_mfma_f32_16x16x32_bf16(a2, bfr[kk], acc[2], 0, 0, 0);
    acc[3] = __builtin_amdgcn_mfma_f32_16x16x32_bf16(a3, bfr[kk], acc[3], 0, 0, 0);
  }

  // ---- attention epilogue ----
  const float cbias = conv_b[layer];
  __syncthreads();                     // all waves done reading tile
  // write ps (bf16, RNE — identical numerics to the old global round-trip)
  // into tile2: addr(row,col) = row*T2S + (row&1)*4 + col  (halves)
  uint16_t* tile2 = tile;
  #pragma unroll
  for (int m = 0; m < 4; ++m)
    #pragma unroll
    for (int r = 0; r < 4; ++r) {
      int row = m * 16 + s * 4 + r;
      tile2[row * T2S + (row & 1) * 4 + 16 * g + m16] =
          f2bf(fmaxf(acc[m][r] + cbias, 0.f));
    }
  // W_att B-frags + b_att (L2-hot)
  v8bf Wf[2][4];
  float batt[4];
  #pragma unroll
  for (int nt = 0; nt < 4; ++nt) {
    batt[nt] = b_att[nt * 16 + m16];
    const float* wr = W_att + (size_t)(nt * 16 + m16) * DD + s * 8;
    #pragma unroll
    for (int kc = 0; kc < 2; ++kc) {
      float4 f0 = ((const float4*)(wr + kc * 32))[0];
      float4 f1 = ((const float4*)(wr + kc * 32))[1];
      Wf[kc][nt] = cvt8(f0, f1);
    }
  }
  __syncthreads();                     // tile2 complete

  // hs-GEMM: wave g owns rows [16g, 16g+16)
  v4f aac[4];
  #pragma unroll
  for (int nt = 0; nt < 4; ++nt) aac[nt] = (v4f){0.f, 0.f, 0.f, 0.f};
  #pragma unroll
  for (int kc = 0; kc < 2; ++kc) {
    int arow = 16 * g + m16;
    const uint16_t* ap = tile2 + arow * T2S + (arow & 1) * 4 + kc * 32 + s * 8;
    union { uint2 u2[2]; v8bf v; } A;
    A.u2[0] = *(const uint2*)(ap);
    A.u2[1] = *(const uint2*)(ap + 4);
    #pragma unroll
    for (int nt = 0; nt < 4; ++nt)
      aac[nt] = __builtin_amdgcn_mfma_f32_16x16x32_bf16(A.v, Wf[kc][nt], aac[nt], 0, 0, 0);
  }
  // bias + relu + mask; stash in per-wave ht (rows local 0..15)
  float vals[4][4];
  float* htw = ht + g * (16 * 68);
  #pragma unroll
  for (int r = 0; r < 4; ++r) {
    int rl = s * 4 + r;
    float pm = pm_s[16 * g + rl];
    #pragma unroll
    for (int nt = 0; nt < 4; ++nt) {
      float v = fmaxf(aac[nt][r] + batt[nt], 0.f) * pm;
      vals[nt][r] = v;
      htw[rl * 68 + nt * 16 + m16] = v;
    }
  }
  // row-dot: lane = row*4 + eq; eq covers 16 e's; same-wave LDS RAW
  {
    int row = lane >> 2, eq = lane & 3;
    const float* hr = htw + row * 68 + eq * 16;
    const float* hv = hv_s + eq * 16;
    float d = 0.f;
    #pragma unroll
    for (int t = 0; t < 4; ++t) {
      float4 hh = *(const float4*)(hr + 4 * t);
      float4 vv = *(const float4*)(hv + 4 * t);
      d = fmaf(hh.x, vv.x, d); d = fmaf(hh.y, vv.y, d);
      d = fmaf(hh.z, vv.z, d); d = fmaf(hh.w, vv.w, d);
    }
    d += __shfl_xor(d, 1);
    d += __shfl_xor(d, 2);
    if (eq == 0) wv_s[g * 16 + row] = tanhf(d);
  }
  // protein partial: pacc[nt] += wt[row] * hs (regs), cross-s reduce
  float pacc[4] = {0.f, 0.f, 0.f, 0.f};
  #pragma unroll
  for (int r = 0; r < 4; ++r) {
    float wt = wv_s[g * 16 + s * 4 + r];
    #pragma unroll
    for (int nt = 0; nt < 4; ++nt)
      pacc[nt] = fmaf(wt, vals[nt][r], pacc[nt]);
  }
  const size_t sl = (size_t)(b * 32 + tl) * 4 + g;
  #pragma unroll
  for (int nt = 0; nt < 4; ++nt) {
    float p = pacc[nt];
    p += __shfl_xor(p, 16);
    p += __shfl_xor(p, 32);
    if (lane < 16) pacc_g[sl * 64 + nt * 16 + lane] = p;
  }
  float mm = (lane < 16) ? pm_s[16 * g + lane] : 0.f;
  mm += __shfl_xor(mm, 1); mm += __shfl_xor(mm, 2);
  mm += __shfl_xor(mm, 4); mm += __shfl_xor(mm, 8);
  if (lane == 0) msum_g[sl] = mm;
}

// --------------------------------------------------- finalize + FC head ----
__global__ __launch_bounds__(128) void attn_final_kernel(
    const float* __restrict__ compound, const float* __restrict__ pacc_part,
    const float* __restrict__ msum_part, const float* __restrict__ W_out,
    const float* __restrict__ b_out, const float* __restrict__ W_int,
    const float* __restrict__ b_int, float* __restrict__ outp)
{
  __shared__ float cat[128];
  __shared__ float cat2[128];
  const int b = blockIdx.x;
  const int tid = threadIdx.x;

  if (tid < 64) {
    float p = 0.f, den = 0.f;
    #pragma unroll 8
    for (int c = 0; c < 128; ++c) {
      p += pacc_part[((size_t)b * 128 + c) * 64 + tid];
      den += msum_part[b * 128 + c];
    }
    cat[tid] = compound[b * DD + tid];
    cat[64 + tid] = p / (den + EPSF);
  }
  __syncthreads();
  {
    float a = b_out[tid];
    const float* wr = W_out + (size_t)tid * 128;
    #pragma unroll 8
    for (int dd = 0; dd < 128; ++dd) a = fmaf(wr[dd], cat[dd], a);
    cat2[tid] = fmaxf(a, 0.f);
  }
  __syncthreads();
  {
    float a = b_out[128 + tid];
    const float* wr = W_out + 128 * 128 + (size_t)tid * 128;
    #pragma unroll 8
    for (int dd = 0; dd < 128; ++dd) a = fmaf(wr[dd], cat2[dd], a);
    __syncthreads();
    cat[tid] = fmaxf(a, 0.f);
  }
  __syncthreads();
  if (tid < 2) {
    float a = b_int[tid];
    const float* wr = W_int + (size_t)tid * 128;
    #pragma unroll 8
    for (int dd = 0; dd < 128; ++dd) a = fmaf(wr[dd], cat[dd], a);
    outp[b * 2 + tid] = a;
  }
}

// -------------------------------------------------------------- launch -----
extern "C" void kernel_launch(void* const* d_in, const int* in_sizes, int n_in,
                              void* d_out, int out_size, void* d_ws, size_t ws_size,
                              hipStream_t stream) {
  const int*   atoms      = (const int*)d_in[0];
  const float* atoms_mask = (const float*)d_in[1];
  const float* adjacency  = (const float*)d_in[2];
  const int*   amino      = (const int*)d_in[3];
  const float* amino_mask = (const float*)d_in[4];
  const float* emb_fp     = (const float*)d_in[5];
  const float* emb_word   = (const float*)d_in[6];
  const float* W_gnn      = (const float*)d_in[7];
  const float* b_gnn      = (const float*)d_in[8];
  const float* conv_k     = (const float*)d_in[9];
  const float* conv_b     = (const float*)d_in[10];
  const float* W_att      = (const float*)d_in[11];
  const float* b_att      = (const float*)d_in[12];
  const float* W_out      = (const float*)d_in[13];
  const float* b_out      = (const float*)d_in[14];
  const float* W_int      = (const float*)d_in[15];
  const float* b_int      = (const float*)d_in[16];
  float* out = (float*)d_out;

  char* ws = (char*)d_ws;
  const size_t ps_bytes = (size_t)BB * LL * DD * 2;   // 64 MB each
  float*    compound  = (float*)ws;                                   // 64 KB
  uint16_t* ps_a      = (uint16_t*)(ws + 65536);
  uint16_t* ps_b      = (uint16_t*)(ws + 65536 + ps_bytes);
  uint16_t* btab      = (uint16_t*)(ws + 65536 + 2 * ps_bytes);       // 90 KB
  float*    hvec_g    = (float*)(ws + 65536 + 2 * ps_bytes + 131072); // 64 KB
  // conv2attn partials alias ps_b: ps_b is dead after conv1 reads it, and
  // conv2attn (sole writer) is ordered after conv1. 8 MB + 128 KB << 64 MB.
  float*    pacc_g = (float*)ps_b;
  float*    msum_g = (float*)((char*)ps_b + (size_t)BB * 32 * 4 * 64 * 4);

  bfrag_kernel<<<3, 64, 0, stream>>>(conv_k, btab);
  // layer 0 + fused gnn (blockIdx.x==0, dispatched first -> hidden under conv)
  conv01_kernel<<<dim3(33, BB), 256, 0, stream>>>(
      ps_a, ps_b, btab, conv_b, amino, emb_word,
      atoms, atoms_mask, adjacency, emb_fp, W_gnn, b_gnn, W_att, b_att,
      compound, hvec_g, 0, 1);
  // layer 1
  conv01_kernel<<<dim3(32, BB), 256, 0, stream>>>(
      ps_b, ps_a, btab, conv_b, amino, emb_word,
      atoms, atoms_mask, adjacency, emb_fp, W_gnn, b_gnn, W_att, b_att,
      compound, hvec_g, 1, 0);
  // layer 2 + fused attention (no ps_b write)
  conv2attn_kernel<<<dim3(32, BB), 256, 0, stream>>>(
      ps_a, btab, conv_b, amino_mask, hvec_g, W_att, b_att, pacc_g, msum_g);
  attn_final_kernel<<<BB, 128, 0, stream>>>(compound, pacc_g, msum_g,
                                            W_out, b_out, W_int, b_int, out);
}

// Round 9
// 442.603 us; speedup vs baseline: 1.1008x; 1.1008x over previous
//
#include <hip/hip_runtime.h>
#include <hip/hip_bf16.h>
#include <cstdint>
#include <cstddef>

#define BB 256
#define NN 128
#define LL 2048
#define DD 64
#define KS 23
#define CPAD 12   // column pad in conv tile (band window requires 11..13)
#define EPSF 1e-6f

typedef __bf16 v8bf __attribute__((ext_vector_type(8)));
typedef float v4f __attribute__((ext_vector_type(4)));

__device__ __forceinline__ float bf2f(uint32_t u) {
  union { uint32_t i; float f; } c; c.i = u << 16; return c.f;
}
__device__ __forceinline__ uint16_t f2bf(float f) {
  union { float f; uint32_t i; } c; c.f = f;
  uint32_t i = c.i;
  return (uint16_t)((i + 0x7fffu + ((i >> 16) & 1u)) >> 16);
}
__device__ __forceinline__ v8bf cvt8(float4 f0, float4 f1) {
  v8bf r;
  r[0] = (__bf16)f0.x; r[1] = (__bf16)f0.y; r[2] = (__bf16)f0.z; r[3] = (__bf16)f0.w;
  r[4] = (__bf16)f1.x; r[5] = (__bf16)f1.y; r[6] = (__bf16)f1.z; r[7] = (__bf16)f1.w;
  return r;
}

// ----------------------------------------------------------- GNN (MFMA) ----
// Standalone (round-8 lesson: fusing it into conv taxes every conv block's
// LDS footprint — 54 KB arena dropped conv occupancy 29->20%).
#define XSS 68    // xs row stride (words)
#define HTS3 136  // hsT row stride (halves)

__global__ __launch_bounds__(256) void gnn_kernel(
    const int* __restrict__ atoms, const float* __restrict__ atoms_mask,
    const float* __restrict__ adj, const float* __restrict__ emb_fp,
    const float* __restrict__ W_gnn, const float* __restrict__ b_gnn,
    const float* __restrict__ W_att, const float* __restrict__ b_att,
    float* __restrict__ compound, float* __restrict__ hvec_g)
{
  __shared__ float xs[NN * XSS];
  __shared__ uint16_t hsT[DD * HTS3];
  __shared__ float mask_s[NN];
  __shared__ float psum[4][64];
  __shared__ float cvec[64];

  const int b = blockIdx.x;
  const int tid = threadIdx.x;
  const int lane = tid & 63;
  const int w = tid >> 6;
  const int m16 = lane & 15;
  const int s = lane >> 4;

  for (int idx = tid; idx < NN * 16; idx += 256) {
    int n = idx >> 4, c4 = idx & 15;
    int a = atoms[b * NN + n];
    float4 v = ((const float4*)(emb_fp + (size_t)a * DD))[c4];
    *(float4*)(xs + n * XSS + c4 * 4) = v;
  }
  if (tid < NN) mask_s[tid] = atoms_mask[b * NN + tid];
  __syncthreads();

  const int row0 = 32 * w;
  for (int layer = 0; layer < 3; ++layer) {
    v8bf Wf[2][4];
    float bias[4];
    const float* Wl = W_gnn + (size_t)layer * DD * DD;
    #pragma unroll
    for (int nt = 0; nt < 4; ++nt) {
      bias[nt] = b_gnn[layer * DD + nt * 16 + m16];
      #pragma unroll
      for (int kc = 0; kc < 2; ++kc) {
        const float* p = Wl + (size_t)(nt * 16 + m16) * DD + kc * 32 + s * 8;
        Wf[kc][nt] = cvt8(((const float4*)p)[0], ((const float4*)p)[1]);
      }
    }
    float4 araw[8][2];
    const float* adjw = adj + ((size_t)b * NN + row0) * NN;
    #pragma unroll
    for (int kc = 0; kc < 4; ++kc)
      #pragma unroll
      for (int mt = 0; mt < 2; ++mt) {
        const float* p = adjw + (size_t)(mt * 16 + m16) * NN + kc * 32 + s * 8;
        araw[kc * 2 + mt][0] = ((const float4*)p)[0];
        araw[kc * 2 + mt][1] = ((const float4*)p)[1];
      }

    v4f acc[2][4];
    #pragma unroll
    for (int mt = 0; mt < 2; ++mt)
      #pragma unroll
      for (int nt = 0; nt < 4; ++nt)
        acc[mt][nt] = (v4f){bias[nt], bias[nt], bias[nt], bias[nt]};
    #pragma unroll
    for (int kc = 0; kc < 2; ++kc) {
      v8bf Axs[2];
      #pragma unroll
      for (int mt = 0; mt < 2; ++mt) {
        const float* p = xs + (size_t)(row0 + mt * 16 + m16) * XSS + kc * 32 + s * 8;
        Axs[mt] = cvt8(((const float4*)p)[0], ((const float4*)p)[1]);
      }
      #pragma unroll
      for (int mt = 0; mt < 2; ++mt)
        #pragma unroll
        for (int nt = 0; nt < 4; ++nt)
          acc[mt][nt] = __builtin_amdgcn_mfma_f32_16x16x32_bf16(
              Axs[mt], Wf[kc][nt], acc[mt][nt], 0, 0, 0);
    }
    __syncthreads();
    #pragma unroll
    for (int mt = 0; mt < 2; ++mt)
      #pragma unroll
      for (int nt = 0; nt < 4; ++nt) {
        int e = nt * 16 + m16;
        int m = row0 + mt * 16 + s * 4;
        union { uint64_t u; __bf16 h[4]; } pk;
        #pragma unroll
        for (int r = 0; r < 4; ++r)
          pk.h[r] = (__bf16)fmaxf(acc[mt][nt][r], 0.f);
        *(uint64_t*)(hsT + (size_t)e * HTS3 + m) = pk.u;
      }
    __syncthreads();

    v4f acc2[2][4];
    #pragma unroll
    for (int mt = 0; mt < 2; ++mt)
      #pragma unroll
      for (int nt = 0; nt < 4; ++nt)
        #pragma unroll
        for (int r = 0; r < 4; ++r)
          acc2[mt][nt][r] = xs[(size_t)(row0 + mt * 16 + s * 4 + r) * XSS + nt * 16 + m16];
    #pragma unroll
    for (int kc = 0; kc < 4; ++kc) {
      v8bf Aa[2];
      #pragma unroll
      for (int mt = 0; mt < 2; ++mt)
        Aa[mt] = cvt8(araw[kc * 2 + mt][0], araw[kc * 2 + mt][1]);
      v8bf Bh[4];
      #pragma unroll
      for (int nt = 0; nt < 4; ++nt)
        Bh[nt] = *(const v8bf*)(hsT + (size_t)(nt * 16 + m16) * HTS3 + kc * 32 + s * 8);
      #pragma unroll
      for (int mt = 0; mt < 2; ++mt)
        #pragma unroll
        for (int nt = 0; nt < 4; ++nt)
          acc2[mt][nt] = __builtin_amdgcn_mfma_f32_16x16x32_bf16(
              Aa[mt], Bh[nt], acc2[mt][nt], 0, 0, 0);
    }
    #pragma unroll
    for (int mt = 0; mt < 2; ++mt)
      #pragma unroll
      for (int nt = 0; nt < 4; ++nt)
        #pragma unroll
        for (int r = 0; r < 4; ++r)
          xs[(size_t)(row0 + mt * 16 + s * 4 + r) * XSS + nt * 16 + m16] = acc2[mt][nt][r];
  }

  float pr = 0.f;
  for (int i = 0; i < 32; ++i) {
    int n = row0 + i;
    pr = fmaf(mask_s[n], xs[(size_t)n * XSS + lane], pr);
  }
  psum[w][lane] = pr;
  __syncthreads();
  if (tid < 64) {
    float ssum = psum[0][tid] + psum[1][tid] + psum[2][tid] + psum[3][tid];
    float den = 0.f;
    #pragma unroll 8
    for (int i = 0; i < NN; ++i) den += mask_s[i];
    float c = ssum / (den + EPSF);
    compound[b * DD + tid] = c;
    cvec[tid] = c;
  }
  __syncthreads();
  if (tid < 64) {
    float a = b_att[tid];
    const float* wr = W_att + (size_t)tid * DD;
    #pragma unroll
    for (int d4 = 0; d4 < 16; ++d4) {
      float4 w4 = ((const float4*)wr)[d4];
      float4 c4 = ((const float4*)cvec)[d4];
      a = fmaf(w4.x, c4.x, a); a = fmaf(w4.y, c4.y, a);
      a = fmaf(w4.z, c4.z, a); a = fmaf(w4.w, c4.w, a);
    }
    hvec_g[b * DD + tid] = fmaxf(a, 0.f);
  }
}

// -------------------------------------------- B-fragment table precompute --
__global__ __launch_bounds__(64) void bfrag_kernel(
    const float* __restrict__ conv_k, uint16_t* __restrict__ btab)
{
  const int layer = blockIdx.x;
  const int lane = threadIdx.x;
  const int s = lane >> 4, n = lane & 15;
  for (int kk = 0; kk < 30; ++kk) {
    int k8 = kk * 4 + s;
    int i = k8 / 5;
    int c8 = k8 - i * 5;
    #pragma unroll
    for (int j = 0; j < 8; ++j) {
      int c = c8 * 8 + j;
      int jj = c - n - 1;
      float v = (i < KS && jj >= 0 && jj < KS)
                    ? conv_k[layer * KS * KS + i * KS + jj] : 0.f;
      btab[(((size_t)layer * 30 + kk) * 64 + lane) * 8 + j] = f2bf(v);
    }
  }
}

// ------------------------------------------------- conv layers 0,1 (MFMA) --
// Proven round-7 shape: 15360 B LDS, occ 2 (occ=4 explodes HBM writes —
// round 6: WRITE 64->360 MB). gmode=1: staging gathers emb_word[amino].
#define TW 88
#define TROWS 86

__global__ __launch_bounds__(256, 2) void conv01_kernel(
    const uint16_t* __restrict__ in, uint16_t* __restrict__ out,
    const uint16_t* __restrict__ btab, const float* __restrict__ conv_b,
    const int* __restrict__ amino, const float* __restrict__ emb_word,
    int layer, int gmode)
{
  __shared__ uint16_t tile[TROWS * TW];
  const int tid = threadIdx.x;
  const int l0 = blockIdx.x * 64;
  const int b  = blockIdx.y;
  const int lane = tid & 63;
  const int g = tid >> 6;

  v8bf bfr[30];
  const uint16_t* bt = btab + (size_t)layer * 30 * 512 + lane * 8;
  #pragma unroll
  for (int kk = 0; kk < 30; ++kk)
    bfr[kk] = *(const v8bf*)(bt + kk * 512);

  for (int i = tid; i < TROWS * 6; i += 256) {
    int r = i / 6, h = i - r * 6;
    int off = (h < 3) ? h * 4 : 76 + (h - 3) * 4;
    *(uint2*)(tile + r * TW + off) = make_uint2(0u, 0u);
  }
  const uint16_t* inb = in + (size_t)b * LL * DD;
  for (int idx = tid; idx < TROWS * 8; idx += 256) {
    int t = idx >> 3, c8 = idx & 7;
    int gl = l0 - 11 + t;
    uint16_t* dst = tile + t * TW + CPAD + c8 * 8;
    if (gl >= 0 && gl < LL) {
      if (gmode) {
        int a = amino[b * LL + gl];
        const float* src = emb_word + (size_t)a * DD + c8 * 8;
        float4 f0 = ((const float4*)src)[0];
        float4 f1 = ((const float4*)src)[1];
        union { uint2 u2[2]; uint16_t h[8]; } pk;
        pk.h[0] = f2bf(f0.x); pk.h[1] = f2bf(f0.y);
        pk.h[2] = f2bf(f0.z); pk.h[3] = f2bf(f0.w);
        pk.h[4] = f2bf(f1.x); pk.h[5] = f2bf(f1.y);
        pk.h[6] = f2bf(f1.z); pk.h[7] = f2bf(f1.w);
        *(uint2*)(dst)     = pk.u2[0];
        *(uint2*)(dst + 4) = pk.u2[1];
      } else {
        uint4 v = *(const uint4*)(inb + (size_t)gl * DD + c8 * 8);
        *(uint2*)(dst)     = make_uint2(v.x, v.y);
        *(uint2*)(dst + 4) = make_uint2(v.z, v.w);
      }
    } else {
      *(uint2*)(dst)     = make_uint2(0u, 0u);
      *(uint2*)(dst + 4) = make_uint2(0u, 0u);
    }
  }
  __syncthreads();

  const int s = lane >> 4;
  const int m16 = lane & 15;
  v4f acc[4];
  #pragma unroll
  for (int m = 0; m < 4; ++m) acc[m] = (v4f){0.f, 0.f, 0.f, 0.f};

  #pragma unroll
  for (int kk = 0; kk < 30; ++kk) {
    int k8 = kk * 4 + s;
    int i = k8 / 5;
    int c8 = k8 - i * 5;
    const uint16_t* ap = tile + (m16 + i) * TW + 16 * g + c8 * 8;
    v8bf a0 = *(const v8bf*)(ap);
    v8bf a1 = *(const v8bf*)(ap + 16 * TW);
    v8bf a2 = *(const v8bf*)(ap + 32 * TW);
    v8bf a3 = *(const v8bf*)(ap + 48 * TW);
    acc[0] = __builtin_amdgcn_mfma_f32_16x16x32_bf16(a0, bfr[kk], acc[0], 0, 0, 0);
    acc[1] = __builtin_amdgcn_mfma_f32_16x16x32_bf16(a1, bfr[kk], acc[1], 0, 0, 0);
    acc[2] = __builtin_amdgcn_mfma_f32_16x16x32_bf16(a2, bfr[kk], acc[2], 0, 0, 0);
    acc[3] = __builtin_amdgcn_mfma_f32_16x16x32_bf16(a3, bfr[kk], acc[3], 0, 0, 0);
  }

  const float bias = conv_b[layer];
  uint16_t* outb = out + ((size_t)b * LL + l0) * DD + 16 * g + m16;
  #pragma unroll
  for (int m = 0; m < 4; ++m) {
    #pragma unroll
    for (int r = 0; r < 4; ++r) {
      int row = m * 16 + s * 4 + r;
      outb[(size_t)row * DD] = f2bf(fmaxf(acc[m][r] + bias, 0.f));
    }
  }
}

// -------------------------------------- conv layer 2 + fused attention -----
// Same LDS footprint as plain conv (tile + 512 B): the tanh row-dot is done
// in registers via s-group shfl reduction (no ht/wv arrays). ps tile
// round-trips through LDS only for the C->A layout change.
#define T2S 68   // tile2 row stride (halves); odd rows shifted +4 (8B align)

__global__ __launch_bounds__(256, 2) void conv2attn_kernel(
    const uint16_t* __restrict__ in, const uint16_t* __restrict__ btab,
    const float* __restrict__ conv_b, const float* __restrict__ amino_mask,
    const float* __restrict__ hvec_g, const float* __restrict__ W_att,
    const float* __restrict__ b_att, float* __restrict__ pacc_g,
    float* __restrict__ msum_g)
{
  __shared__ uint16_t tile[TROWS * TW];   // tile2 aliases this
  __shared__ float pm_s[64];
  __shared__ float hv_s[64];

  const int layer = 2;
  const int tid = threadIdx.x;
  const int tl = blockIdx.x;
  const int l0 = tl * 64;
  const int b  = blockIdx.y;
  const int lane = tid & 63;
  const int g = tid >> 6;

  v8bf bfr[30];
  const uint16_t* bt = btab + (size_t)layer * 30 * 512 + lane * 8;
  #pragma unroll
  for (int kk = 0; kk < 30; ++kk)
    bfr[kk] = *(const v8bf*)(bt + kk * 512);

  for (int i = tid; i < TROWS * 6; i += 256) {
    int r = i / 6, h = i - r * 6;
    int off = (h < 3) ? h * 4 : 76 + (h - 3) * 4;
    *(uint2*)(tile + r * TW + off) = make_uint2(0u, 0u);
  }
  const uint16_t* inb = in + (size_t)b * LL * DD;
  for (int idx = tid; idx < TROWS * 8; idx += 256) {
    int t = idx >> 3, c8 = idx & 7;
    int gl = l0 - 11 + t;
    uint16_t* dst = tile + t * TW + CPAD + c8 * 8;
    if (gl >= 0 && gl < LL) {
      uint4 v = *(const uint4*)(inb + (size_t)gl * DD + c8 * 8);
      *(uint2*)(dst)     = make_uint2(v.x, v.y);
      *(uint2*)(dst + 4) = make_uint2(v.z, v.w);
    } else {
      *(uint2*)(dst)     = make_uint2(0u, 0u);
      *(uint2*)(dst + 4) = make_uint2(0u, 0u);
    }
  }
  if (tid < 64) {
    pm_s[tid] = amino_mask[(size_t)b * LL + l0 + tid];
    hv_s[tid] = hvec_g[b * DD + tid];
  }
  __syncthreads();

  const int s = lane >> 4;
  const int m16 = lane & 15;
  v4f acc[4];
  #pragma unroll
  for (int m = 0; m < 4; ++m) acc[m] = (v4f){0.f, 0.f, 0.f, 0.f};

  #pragma unroll
  for (int kk = 0; kk < 30; ++kk) {
    int k8 = kk * 4 + s;
    int i = k8 / 5;
    int c8 = k8 - i * 5;
    const uint16_t* ap = tile + (m16 + i) * TW + 16 * g + c8 * 8;
    v8bf a0 = *(const v8bf*)(ap);
    v8bf a1 = *(const v8bf*)(ap + 16 * TW);
    v8bf a2 = *(const v8bf*)(ap + 32 * TW);
    v8bf a3 = *(const v8bf*)(ap + 48 * TW);
    acc[0] = __builtin_amdgcn_mfma_f32_16x16x32_bf16(a0, bfr[kk], acc[0], 0, 0, 0);
    acc[1] = __builtin_amdgcn_mfma_f32_16x16x32_bf16(a1, bfr[kk], acc[1], 0, 0, 0);
    acc[2] = __builtin_amdgcn_mfma_f32_16x16x32_bf16(a2, bfr[kk], acc[2], 0, 0, 0);
    acc[3] = __builtin_amdgcn_mfma_f32_16x16x32_bf16(a3, bfr[kk], acc[3], 0, 0, 0);
  }

  // ---- attention epilogue ----
  const float cbias = conv_b[layer];
  __syncthreads();                     // all waves done reading tile
  // ps (bf16, RNE — identical numerics to the old global round-trip)
  uint16_t* tile2 = tile;
  #pragma unroll
  for (int m = 0; m < 4; ++m)
    #pragma unroll
    for (int r = 0; r < 4; ++r) {
      int row = m * 16 + s * 4 + r;
      tile2[row * T2S + (row & 1) * 4 + 16 * g + m16] =
          f2bf(fmaxf(acc[m][r] + cbias, 0.f));
    }
  // W_att B-frags + b_att (L2-hot) — loaded while tile2 settles
  v8bf Wf[2][4];
  float batt[4];
  #pragma unroll
  for (int nt = 0; nt < 4; ++nt) {
    batt[nt] = b_att[nt * 16 + m16];
    const float* wr = W_att + (size_t)(nt * 16 + m16) * DD + s * 8;
    #pragma unroll
    for (int kc = 0; kc < 2; ++kc) {
      float4 f0 = ((const float4*)(wr + kc * 32))[0];
      float4 f1 = ((const float4*)(wr + kc * 32))[1];
      Wf[kc][nt] = cvt8(f0, f1);
    }
  }
  __syncthreads();                     // tile2 complete

  // hs-GEMM: wave g owns rows [16g, 16g+16)
  v4f aac[4];
  #pragma unroll
  for (int nt = 0; nt < 4; ++nt) aac[nt] = (v4f){0.f, 0.f, 0.f, 0.f};
  #pragma unroll
  for (int kc = 0; kc < 2; ++kc) {
    int arow = 16 * g + m16;
    const uint16_t* ap = tile2 + arow * T2S + (arow & 1) * 4 + kc * 32 + s * 8;
    union { uint2 u2[2]; v8bf v; } A;
    A.u2[0] = *(const uint2*)(ap);
    A.u2[1] = *(const uint2*)(ap + 4);
    #pragma unroll
    for (int nt = 0; nt < 4; ++nt)
      aac[nt] = __builtin_amdgcn_mfma_f32_16x16x32_bf16(A.v, Wf[kc][nt], aac[nt], 0, 0, 0);
  }
  // bias + relu + mask (rows 16g + s*4 + r, col nt*16+m16)
  float vals[4][4];
  float hvr[4];
  #pragma unroll
  for (int nt = 0; nt < 4; ++nt) hvr[nt] = hv_s[nt * 16 + m16];
  #pragma unroll
  for (int r = 0; r < 4; ++r) {
    float pm = pm_s[16 * g + s * 4 + r];
    #pragma unroll
    for (int nt = 0; nt < 4; ++nt)
      vals[nt][r] = fmaxf(aac[nt][r] + batt[nt], 0.f) * pm;
  }
  // register row-dot: d[r] = sum_e hs[row][e]*hv[e], reduced over the 16
  // lanes of this s-group (lane = s*16 + m16; xor 1,2,4,8 stays in-group)
  float pacc[4] = {0.f, 0.f, 0.f, 0.f};
  #pragma unroll
  for (int r = 0; r < 4; ++r) {
    float d = 0.f;
    #pragma unroll
    for (int nt = 0; nt < 4; ++nt) d = fmaf(vals[nt][r], hvr[nt], d);
    d += __shfl_xor(d, 1);
    d += __shfl_xor(d, 2);
    d += __shfl_xor(d, 4);
    d += __shfl_xor(d, 8);
    float wt = tanhf(d);
    #pragma unroll
    for (int nt = 0; nt < 4; ++nt)
      pacc[nt] = fmaf(wt, vals[nt][r], pacc[nt]);
  }
  // cross-s reduce -> full column sums over this wave's 16 rows
  const size_t sl = (size_t)(b * 32 + tl) * 4 + g;
  #pragma unroll
  for (int nt = 0; nt < 4; ++nt) {
    float p = pacc[nt];
    p += __shfl_xor(p, 16);
    p += __shfl_xor(p, 32);
    if (lane < 16) pacc_g[sl * 64 + nt * 16 + lane] = p;
  }
  float mm = (lane < 16) ? pm_s[16 * g + lane] : 0.f;
  mm += __shfl_xor(mm, 1); mm += __shfl_xor(mm, 2);
  mm += __shfl_xor(mm, 4); mm += __shfl_xor(mm, 8);
  if (lane == 0) msum_g[sl] = mm;
}

// --------------------------------------------------- finalize + FC head ----
__global__ __launch_bounds__(128) void attn_final_kernel(
    const float* __restrict__ compound, const float* __restrict__ pacc_part,
    const float* __restrict__ msum_part, const float* __restrict__ W_out,
    const float* __restrict__ b_out, const float* __restrict__ W_int,
    const float* __restrict__ b_int, float* __restrict__ outp)
{
  __shared__ float cat[128];
  __shared__ float cat2[128];
  const int b = blockIdx.x;
  const int tid = threadIdx.x;

  if (tid < 64) {
    float p = 0.f, den = 0.f;
    #pragma unroll 8
    for (int c = 0; c < 128; ++c) {
      p += pacc_part[((size_t)b * 128 + c) * 64 + tid];
      den += msum_part[b * 128 + c];
    }
    cat[tid] = compound[b * DD + tid];
    cat[64 + tid] = p / (den + EPSF);
  }
  __syncthreads();
  {
    float a = b_out[tid];
    const float* wr = W_out + (size_t)tid * 128;
    #pragma unroll 8
    for (int dd = 0; dd < 128; ++dd) a = fmaf(wr[dd], cat[dd], a);
    cat2[tid] = fmaxf(a, 0.f);
  }
  __syncthreads();
  {
    float a = b_out[128 + tid];
    const float* wr = W_out + 128 * 128 + (size_t)tid * 128;
    #pragma unroll 8
    for (int dd = 0; dd < 128; ++dd) a = fmaf(wr[dd], cat2[dd], a);
    __syncthreads();
    cat[tid] = fmaxf(a, 0.f);
  }
  __syncthreads();
  if (tid < 2) {
    float a = b_int[tid];
    const float* wr = W_int + (size_t)tid * 128;
    #pragma unroll 8
    for (int dd = 0; dd < 128; ++dd) a = fmaf(wr[dd], cat[dd], a);
    outp[b * 2 + tid] = a;
  }
}

// -------------------------------------------------------------- launch -----
extern "C" void kernel_launch(void* const* d_in, const int* in_sizes, int n_in,
                              void* d_out, int out_size, void* d_ws, size_t ws_size,
                              hipStream_t stream) {
  const int*   atoms      = (const int*)d_in[0];
  const float* atoms_mask = (const float*)d_in[1];
  const float* adjacency  = (const float*)d_in[2];
  const int*   amino      = (const int*)d_in[3];
  const float* amino_mask = (const float*)d_in[4];
  const float* emb_fp     = (const float*)d_in[5];
  const float* emb_word   = (const float*)d_in[6];
  const float* W_gnn      = (const float*)d_in[7];
  const float* b_gnn      = (const float*)d_in[8];
  const float* conv_k     = (const float*)d_in[9];
  const float* conv_b     = (const float*)d_in[10];
  const float* W_att      = (const float*)d_in[11];
  const float* b_att      = (const float*)d_in[12];
  const float* W_out      = (const float*)d_in[13];
  const float* b_out      = (const float*)d_in[14];
  const float* W_int      = (const float*)d_in[15];
  const float* b_int      = (const float*)d_in[16];
  float* out = (float*)d_out;

  char* ws = (char*)d_ws;
  const size_t ps_bytes = (size_t)BB * LL * DD * 2;   // 64 MB each
  float*    compound  = (float*)ws;                                   // 64 KB
  uint16_t* ps_a      = (uint16_t*)(ws + 65536);
  uint16_t* ps_b      = (uint16_t*)(ws + 65536 + ps_bytes);
  uint16_t* btab      = (uint16_t*)(ws + 65536 + 2 * ps_bytes);       // 90 KB
  float*    hvec_g    = (float*)(ws + 65536 + 2 * ps_bytes + 131072); // 64 KB
  // conv2attn partials alias ps_b: ps_b is dead after conv1 reads it, and
  // conv2attn (sole writer) is ordered after conv1.
  float*    pacc_g = (float*)ps_b;
  float*    msum_g = (float*)((char*)ps_b + (size_t)BB * 32 * 4 * 64 * 4);

  bfrag_kernel<<<3, 64, 0, stream>>>(conv_k, btab);
  gnn_kernel<<<BB, 256, 0, stream>>>(atoms, atoms_mask, adjacency, emb_fp,
                                     W_gnn, b_gnn, W_att, b_att,
                                     compound, hvec_g);
  // layer 0 (gathers emb_word[amino] in staging), layer 1
  conv01_kernel<<<dim3(32, BB), 256, 0, stream>>>(ps_a, ps_b, btab, conv_b,
                                                  amino, emb_word, 0, 1);
  conv01_kernel<<<dim3(32, BB), 256, 0, stream>>>(ps_b, ps_a, btab, conv_b,
                                                  amino, emb_word, 1, 0);
  // layer 2 + fused attention (no ps write)
  conv2attn_kernel<<<dim3(32, BB), 256, 0, stream>>>(
      ps_a, btab, conv_b, amino_mask, hvec_g, W_att, b_att, pacc_g, msum_g);
  attn_final_kernel<<<BB, 128, 0, stream>>>(compound, pacc_g, msum_g,
                                            W_out, b_out, W_int, b_int, out);
}

// Round 10
// 405.477 us; speedup vs baseline: 1.2016x; 1.0916x over previous
//
#include <hip/hip_runtime.h>
#include <hip/hip_bf16.h>
#include <cstdint>
#include <cstddef>

#define BB 256
#define NN 128
#define LL 2048
#define DD 64
#define KS 23
#define CPAD 12   // column pad in conv tile (band window requires 11..13)
#define EPSF 1e-6f
#define ACH 8     // attention L-chunks: block covers 256 rows

typedef __bf16 v8bf __attribute__((ext_vector_type(8)));
typedef float v4f __attribute__((ext_vector_type(4)));

__device__ __forceinline__ float bf2f(uint32_t u) {
  union { uint32_t i; float f; } c; c.i = u << 16; return c.f;
}
__device__ __forceinline__ uint16_t f2bf(float f) {
  union { float f; uint32_t i; } c; c.f = f;
  uint32_t i = c.i;
  return (uint16_t)((i + 0x7fffu + ((i >> 16) & 1u)) >> 16);
}
__device__ __forceinline__ v8bf cvt8(float4 f0, float4 f1) {
  v8bf r;
  r[0] = (__bf16)f0.x; r[1] = (__bf16)f0.y; r[2] = (__bf16)f0.z; r[3] = (__bf16)f0.w;
  r[4] = (__bf16)f1.x; r[5] = (__bf16)f1.y; r[6] = (__bf16)f1.z; r[7] = (__bf16)f1.w;
  return r;
}

// ----------------------------------------------------------- GNN (MFMA) ----
// Standalone (round-8: fusing into conv taxed every conv block's LDS).
// Blocks 0..2 additionally build the conv B-fragment table (kills the
// separate bfrag dispatch; gnn completes before conv0 launches).
#define XSS 68    // xs row stride (words)
#define HTS3 136  // hsT row stride (halves)

__global__ __launch_bounds__(256) void gnn_kernel(
    const int* __restrict__ atoms, const float* __restrict__ atoms_mask,
    const float* __restrict__ adj, const float* __restrict__ emb_fp,
    const float* __restrict__ W_gnn, const float* __restrict__ b_gnn,
    const float* __restrict__ W_att, const float* __restrict__ b_att,
    const float* __restrict__ conv_k, uint16_t* __restrict__ btab,
    float* __restrict__ compound, float* __restrict__ hvec_g)
{
  __shared__ float xs[NN * XSS];
  __shared__ uint16_t hsT[DD * HTS3];
  __shared__ float mask_s[NN];
  __shared__ float psum[4][64];
  __shared__ float cvec[64];

  const int b = blockIdx.x;
  const int tid = threadIdx.x;
  const int lane = tid & 63;
  const int w = tid >> 6;
  const int m16 = lane & 15;
  const int s = lane >> 4;

  for (int idx = tid; idx < NN * 16; idx += 256) {
    int n = idx >> 4, c4 = idx & 15;
    int a = atoms[b * NN + n];
    float4 v = ((const float4*)(emb_fp + (size_t)a * DD))[c4];
    *(float4*)(xs + n * XSS + c4 * 4) = v;
  }
  if (tid < NN) mask_s[tid] = atoms_mask[b * NN + tid];
  __syncthreads();

  const int row0 = 32 * w;
  for (int layer = 0; layer < 3; ++layer) {
    v8bf Wf[2][4];
    float bias[4];
    const float* Wl = W_gnn + (size_t)layer * DD * DD;
    #pragma unroll
    for (int nt = 0; nt < 4; ++nt) {
      bias[nt] = b_gnn[layer * DD + nt * 16 + m16];
      #pragma unroll
      for (int kc = 0; kc < 2; ++kc) {
        const float* p = Wl + (size_t)(nt * 16 + m16) * DD + kc * 32 + s * 8;
        Wf[kc][nt] = cvt8(((const float4*)p)[0], ((const float4*)p)[1]);
      }
    }
    float4 araw[8][2];
    const float* adjw = adj + ((size_t)b * NN + row0) * NN;
    #pragma unroll
    for (int kc = 0; kc < 4; ++kc)
      #pragma unroll
      for (int mt = 0; mt < 2; ++mt) {
        const float* p = adjw + (size_t)(mt * 16 + m16) * NN + kc * 32 + s * 8;
        araw[kc * 2 + mt][0] = ((const float4*)p)[0];
        araw[kc * 2 + mt][1] = ((const float4*)p)[1];
      }

    v4f acc[2][4];
    #pragma unroll
    for (int mt = 0; mt < 2; ++mt)
      #pragma unroll
      for (int nt = 0; nt < 4; ++nt)
        acc[mt][nt] = (v4f){bias[nt], bias[nt], bias[nt], bias[nt]};
    #pragma unroll
    for (int kc = 0; kc < 2; ++kc) {
      v8bf Axs[2];
      #pragma unroll
      for (int mt = 0; mt < 2; ++mt) {
        const float* p = xs + (size_t)(row0 + mt * 16 + m16) * XSS + kc * 32 + s * 8;
        Axs[mt] = cvt8(((const float4*)p)[0], ((const float4*)p)[1]);
      }
      #pragma unroll
      for (int mt = 0; mt < 2; ++mt)
        #pragma unroll
        for (int nt = 0; nt < 4; ++nt)
          acc[mt][nt] = __builtin_amdgcn_mfma_f32_16x16x32_bf16(
              Axs[mt], Wf[kc][nt], acc[mt][nt], 0, 0, 0);
    }
    __syncthreads();
    #pragma unroll
    for (int mt = 0; mt < 2; ++mt)
      #pragma unroll
      for (int nt = 0; nt < 4; ++nt) {
        int e = nt * 16 + m16;
        int m = row0 + mt * 16 + s * 4;
        union { uint64_t u; __bf16 h[4]; } pk;
        #pragma unroll
        for (int r = 0; r < 4; ++r)
          pk.h[r] = (__bf16)fmaxf(acc[mt][nt][r], 0.f);
        *(uint64_t*)(hsT + (size_t)e * HTS3 + m) = pk.u;
      }
    __syncthreads();

    v4f acc2[2][4];
    #pragma unroll
    for (int mt = 0; mt < 2; ++mt)
      #pragma unroll
      for (int nt = 0; nt < 4; ++nt)
        #pragma unroll
        for (int r = 0; r < 4; ++r)
          acc2[mt][nt][r] = xs[(size_t)(row0 + mt * 16 + s * 4 + r) * XSS + nt * 16 + m16];
    #pragma unroll
    for (int kc = 0; kc < 4; ++kc) {
      v8bf Aa[2];
      #pragma unroll
      for (int mt = 0; mt < 2; ++mt)
        Aa[mt] = cvt8(araw[kc * 2 + mt][0], araw[kc * 2 + mt][1]);
      v8bf Bh[4];
      #pragma unroll
      for (int nt = 0; nt < 4; ++nt)
        Bh[nt] = *(const v8bf*)(hsT + (size_t)(nt * 16 + m16) * HTS3 + kc * 32 + s * 8);
      #pragma unroll
      for (int mt = 0; mt < 2; ++mt)
        #pragma unroll
        for (int nt = 0; nt < 4; ++nt)
          acc2[mt][nt] = __builtin_amdgcn_mfma_f32_16x16x32_bf16(
              Aa[mt], Bh[nt], acc2[mt][nt], 0, 0, 0);
    }
    #pragma unroll
    for (int mt = 0; mt < 2; ++mt)
      #pragma unroll
      for (int nt = 0; nt < 4; ++nt)
        #pragma unroll
        for (int r = 0; r < 4; ++r)
          xs[(size_t)(row0 + mt * 16 + s * 4 + r) * XSS + nt * 16 + m16] = acc2[mt][nt][r];
  }

  float pr = 0.f;
  for (int i = 0; i < 32; ++i) {
    int n = row0 + i;
    pr = fmaf(mask_s[n], xs[(size_t)n * XSS + lane], pr);
  }
  psum[w][lane] = pr;
  __syncthreads();
  if (tid < 64) {
    float ssum = psum[0][tid] + psum[1][tid] + psum[2][tid] + psum[3][tid];
    float den = 0.f;
    #pragma unroll 8
    for (int i = 0; i < NN; ++i) den += mask_s[i];
    float c = ssum / (den + EPSF);
    compound[b * DD + tid] = c;
    cvec[tid] = c;
  }
  __syncthreads();
  if (tid < 64) {
    float a = b_att[tid];
    const float* wr = W_att + (size_t)tid * DD;
    #pragma unroll
    for (int d4 = 0; d4 < 16; ++d4) {
      float4 w4 = ((const float4*)wr)[d4];
      float4 c4 = ((const float4*)cvec)[d4];
      a = fmaf(w4.x, c4.x, a); a = fmaf(w4.y, c4.y, a);
      a = fmaf(w4.z, c4.z, a); a = fmaf(w4.w, c4.w, a);
    }
    hvec_g[b * DD + tid] = fmaxf(a, 0.f);
  }

  // ---- bfrag tail (blocks 0..2 only; layer = b) ----
  if (b < 3) {
    for (int kk = w; kk < 30; kk += 4) {
      int k8 = kk * 4 + s;
      int i = k8 / 5;
      int c8k = k8 - i * 5;
      #pragma unroll
      for (int j = 0; j < 8; ++j) {
        int c = c8k * 8 + j;
        int jj = c - m16 - 1;
        float v = (i < KS && jj >= 0 && jj < KS)
                      ? conv_k[b * KS * KS + i * KS + jj] : 0.f;
        btab[(((size_t)b * 30 + kk) * 64 + lane) * 8 + j] = f2bf(v);
      }
    }
  }
}

// --------------------------------------------------------------- conv ------
// occ=3 now safe: C-stores are staged through LDS (aliasing the dead input
// tile) and issued as full-line dwordx4 — immune to the round-6 partial-line
// write amplification. gmode=1: staging gathers emb_word[amino] (layer 0).
#define TW 88
#define TROWS 86
#define OTS 72   // output-stage row stride in halves (16B-aligned rows)

__global__ __launch_bounds__(256, 3) void conv_kernel(
    const uint16_t* __restrict__ in, uint16_t* __restrict__ out,
    const uint16_t* __restrict__ btab, const float* __restrict__ conv_b,
    const int* __restrict__ amino, const float* __restrict__ emb_word,
    int layer, int gmode)
{
  __shared__ uint16_t tile[TROWS * TW];   // out-stage (64*OTS) aliases this
  const int tid = threadIdx.x;
  const int l0 = blockIdx.x * 64;
  const int b  = blockIdx.y;
  const int lane = tid & 63;
  const int g = tid >> 6;

  v8bf bfr[30];
  const uint16_t* bt = btab + (size_t)layer * 30 * 512 + lane * 8;
  #pragma unroll
  for (int kk = 0; kk < 30; ++kk)
    bfr[kk] = *(const v8bf*)(bt + kk * 512);

  for (int i = tid; i < TROWS * 6; i += 256) {
    int r = i / 6, h = i - r * 6;
    int off = (h < 3) ? h * 4 : 76 + (h - 3) * 4;
    *(uint2*)(tile + r * TW + off) = make_uint2(0u, 0u);
  }
  const uint16_t* inb = in + (size_t)b * LL * DD;
  for (int idx = tid; idx < TROWS * 8; idx += 256) {
    int t = idx >> 3, c8 = idx & 7;
    int gl = l0 - 11 + t;
    uint16_t* dst = tile + t * TW + CPAD + c8 * 8;
    if (gl >= 0 && gl < LL) {
      if (gmode) {
        int a = amino[b * LL + gl];
        const float* src = emb_word + (size_t)a * DD + c8 * 8;
        float4 f0 = ((const float4*)src)[0];
        float4 f1 = ((const float4*)src)[1];
        union { uint2 u2[2]; uint16_t h[8]; } pk;
        pk.h[0] = f2bf(f0.x); pk.h[1] = f2bf(f0.y);
        pk.h[2] = f2bf(f0.z); pk.h[3] = f2bf(f0.w);
        pk.h[4] = f2bf(f1.x); pk.h[5] = f2bf(f1.y);
        pk.h[6] = f2bf(f1.z); pk.h[7] = f2bf(f1.w);
        *(uint2*)(dst)     = pk.u2[0];
        *(uint2*)(dst + 4) = pk.u2[1];
      } else {
        uint4 v = *(const uint4*)(inb + (size_t)gl * DD + c8 * 8);
        *(uint2*)(dst)     = make_uint2(v.x, v.y);
        *(uint2*)(dst + 4) = make_uint2(v.z, v.w);
      }
    } else {
      *(uint2*)(dst)     = make_uint2(0u, 0u);
      *(uint2*)(dst + 4) = make_uint2(0u, 0u);
    }
  }
  __syncthreads();

  const int s = lane >> 4;
  const int m16 = lane & 15;
  v4f acc[4];
  #pragma unroll
  for (int m = 0; m < 4; ++m) acc[m] = (v4f){0.f, 0.f, 0.f, 0.f};

  #pragma unroll
  for (int kk = 0; kk < 30; ++kk) {
    int k8 = kk * 4 + s;
    int i = k8 / 5;
    int c8 = k8 - i * 5;
    const uint16_t* ap = tile + (m16 + i) * TW + 16 * g + c8 * 8;
    v8bf a0 = *(const v8bf*)(ap);
    v8bf a1 = *(const v8bf*)(ap + 16 * TW);
    v8bf a2 = *(const v8bf*)(ap + 32 * TW);
    v8bf a3 = *(const v8bf*)(ap + 48 * TW);
    acc[0] = __builtin_amdgcn_mfma_f32_16x16x32_bf16(a0, bfr[kk], acc[0], 0, 0, 0);
    acc[1] = __builtin_amdgcn_mfma_f32_16x16x32_bf16(a1, bfr[kk], acc[1], 0, 0, 0);
    acc[2] = __builtin_amdgcn_mfma_f32_16x16x32_bf16(a2, bfr[kk], acc[2], 0, 0, 0);
    acc[3] = __builtin_amdgcn_mfma_f32_16x16x32_bf16(a3, bfr[kk], acc[3], 0, 0, 0);
  }

  // ---- coalesced store epilogue (stage via LDS, alias input tile) ----
  const float bias = conv_b[layer];
  __syncthreads();                 // all waves done reading tile
  uint16_t* ot = tile;             // 64 * OTS halves = 9216 B < 15136 B
  #pragma unroll
  for (int m = 0; m < 4; ++m)
    #pragma unroll
    for (int r = 0; r < 4; ++r) {
      int row = m * 16 + s * 4 + r;
      ot[row * OTS + 16 * g + m16] = f2bf(fmaxf(acc[m][r] + bias, 0.f));
    }
  __syncthreads();
  uint16_t* outb = out + ((size_t)b * LL + l0) * DD;
  for (int i = tid; i < 512; i += 256) {
    int row = i >> 3, c8 = i & 7;
    uint4 v = *(const uint4*)(ot + row * OTS + c8 * 8);
    *(uint4*)(outb + (size_t)row * DD + c8 * 8) = v;
  }
}

// --------------------------------------------- attention partials (MFMA) ---
#define HTS2 66

__global__ __launch_bounds__(256) void attn_part_kernel(
    const uint16_t* __restrict__ ps, const float* __restrict__ amino_mask,
    const float* __restrict__ hvec_g, const float* __restrict__ W_att,
    const float* __restrict__ b_att, float* __restrict__ pacc_part,
    float* __restrict__ msum_part)
{
  __shared__ float ht[4][32 * HTS2];
  __shared__ float pm_s[4][64];
  __shared__ float wv_s[4][32];
  __shared__ float hv_s[64];

  const int chunk = blockIdx.x;
  const int b = blockIdx.y;
  const int tid = threadIdx.x;
  const int lane = tid & 63;
  const int w = tid >> 6;
  const int m16 = lane & 15;
  const int s = lane >> 4;

  v8bf bfrB[2][4];
  float bias[4];
  #pragma unroll
  for (int nt = 0; nt < 4; ++nt) {
    bias[nt] = b_att[nt * 16 + m16];
    const float* wr = W_att + (size_t)(nt * 16 + m16) * DD + s * 8;
    #pragma unroll
    for (int kc = 0; kc < 2; ++kc) {
      float4 f0 = ((const float4*)(wr + kc * 32))[0];
      float4 f1 = ((const float4*)(wr + kc * 32))[1];
      bfrB[kc][nt] = cvt8(f0, f1);
    }
  }
  if (tid < 64) hv_s[tid] = hvec_g[b * DD + tid];

  const int rowbase = chunk * 256 + w * 64;
  const float* pmb = amino_mask + (size_t)b * LL;
  pm_s[w][lane] = pmb[rowbase + lane];
  const float macc = pm_s[w][lane];
  __syncthreads();

  float pacc[4] = {0.f, 0.f, 0.f, 0.f};
  const uint16_t* psb = ps + ((size_t)b * LL + rowbase) * DD;

  #pragma unroll
  for (int step = 0; step < 2; ++step) {
    const uint16_t* pr = psb + (size_t)step * 32 * DD;
    v8bf A[2][2];
    #pragma unroll
    for (int mt = 0; mt < 2; ++mt)
      #pragma unroll
      for (int kc = 0; kc < 2; ++kc)
        A[mt][kc] = *(const v8bf*)(pr + (mt * 16 + m16) * DD + kc * 32 + s * 8);

    v4f acc[2][4];
    #pragma unroll
    for (int mt = 0; mt < 2; ++mt)
      #pragma unroll
      for (int nt = 0; nt < 4; ++nt)
        acc[mt][nt] = (v4f){0.f, 0.f, 0.f, 0.f};
    #pragma unroll
    for (int kc = 0; kc < 2; ++kc)
      #pragma unroll
      for (int mt = 0; mt < 2; ++mt)
        #pragma unroll
        for (int nt = 0; nt < 4; ++nt)
          acc[mt][nt] = __builtin_amdgcn_mfma_f32_16x16x32_bf16(
              A[mt][kc], bfrB[kc][nt], acc[mt][nt], 0, 0, 0);

    float vals[2][4][4];
    float* htw = ht[w];
    #pragma unroll
    for (int mt = 0; mt < 2; ++mt)
      #pragma unroll
      for (int r = 0; r < 4; ++r) {
        int row = mt * 16 + s * 4 + r;
        float pm = pm_s[w][step * 32 + row];
        #pragma unroll
        for (int nt = 0; nt < 4; ++nt) {
          float v = fmaxf(acc[mt][nt][r] + bias[nt], 0.f) * pm;
          vals[mt][nt][r] = v;
          htw[row * HTS2 + nt * 16 + m16] = v;
        }
      }
    __syncthreads();

    {
      int row = lane & 31, eh = lane >> 5;
      const float* hr = ht[w] + row * HTS2 + eh * 32;
      const float* hv = hv_s + eh * 32;
      float d = 0.f;
      #pragma unroll
      for (int t = 0; t < 8; ++t) {
        float4 hh = *(const float4*)(hr + 4 * t);
        float4 vv = *(const float4*)(hv + 4 * t);
        d = fmaf(hh.x, vv.x, d); d = fmaf(hh.y, vv.y, d);
        d = fmaf(hh.z, vv.z, d); d = fmaf(hh.w, vv.w, d);
      }
      d += __shfl_xor(d, 32);
      float wt = tanhf(d);
      if (lane < 32) wv_s[w][row] = wt;
    }
    __syncthreads();

    #pragma unroll
    for (int mt = 0; mt < 2; ++mt)
      #pragma unroll
      for (int r = 0; r < 4; ++r) {
        float wt = wv_s[w][mt * 16 + s * 4 + r];
        #pragma unroll
        for (int nt = 0; nt < 4; ++nt)
          pacc[nt] = fmaf(wt, vals[mt][nt][r], pacc[nt]);
      }
    __syncthreads();
  }

  const size_t idx = ((size_t)b * ACH + chunk) * 4 + w;
  #pragma unroll
  for (int nt = 0; nt < 4; ++nt) {
    float p = pacc[nt];
    p += __shfl_xor(p, 16);
    p += __shfl_xor(p, 32);
    if (m16 == lane)
      pacc_part[idx * 64 + nt * 16 + lane] = p;
  }
  float m = macc;
  #pragma unroll
  for (int off = 1; off < 64; off <<= 1) m += __shfl_xor(m, off);
  if (lane == 0) msum_part[idx] = m;
}

// --------------------------------------------------- finalize + FC head ----
__global__ __launch_bounds__(128) void attn_final_kernel(
    const float* __restrict__ compound, const float* __restrict__ pacc_part,
    const float* __restrict__ msum_part, const float* __restrict__ W_out,
    const float* __restrict__ b_out, const float* __restrict__ W_int,
    const float* __restrict__ b_int, float* __restrict__ outp)
{
  __shared__ float cat[128];
  __shared__ float cat2[128];
  const int b = blockIdx.x;
  const int tid = threadIdx.x;

  if (tid < 64) {
    float p = 0.f, den = 0.f;
    #pragma unroll 4
    for (int c = 0; c < ACH * 4; ++c) {
      p += pacc_part[((size_t)b * ACH * 4 + c) * 64 + tid];
      den += msum_part[b * ACH * 4 + c];
    }
    cat[tid] = compound[b * DD + tid];
    cat[64 + tid] = p / (den + EPSF);
  }
  __syncthreads();
  {
    float a = b_out[tid];
    const float* wr = W_out + (size_t)tid * 128;
    #pragma unroll 8
    for (int dd = 0; dd < 128; ++dd) a = fmaf(wr[dd], cat[dd], a);
    cat2[tid] = fmaxf(a, 0.f);
  }
  __syncthreads();
  {
    float a = b_out[128 + tid];
    const float* wr = W_out + 128 * 128 + (size_t)tid * 128;
    #pragma unroll 8
    for (int dd = 0; dd < 128; ++dd) a = fmaf(wr[dd], cat2[dd], a);
    __syncthreads();
    cat[tid] = fmaxf(a, 0.f);
  }
  __syncthreads();
  if (tid < 2) {
    float a = b_int[tid];
    const float* wr = W_int + (size_t)tid * 128;
    #pragma unroll 8
    for (int dd = 0; dd < 128; ++dd) a = fmaf(wr[dd], cat[dd], a);
    outp[b * 2 + tid] = a;
  }
}

// -------------------------------------------------------------- launch -----
extern "C" void kernel_launch(void* const* d_in, const int* in_sizes, int n_in,
                              void* d_out, int out_size, void* d_ws, size_t ws_size,
                              hipStream_t stream) {
  const int*   atoms      = (const int*)d_in[0];
  const float* atoms_mask = (const float*)d_in[1];
  const float* adjacency  = (const float*)d_in[2];
  const int*   amino      = (const int*)d_in[3];
  const float* amino_mask = (const float*)d_in[4];
  const float* emb_fp     = (const float*)d_in[5];
  const float* emb_word   = (const float*)d_in[6];
  const float* W_gnn      = (const float*)d_in[7];
  const float* b_gnn      = (const float*)d_in[8];
  const float* conv_k     = (const float*)d_in[9];
  const float* conv_b     = (const float*)d_in[10];
  const float* W_att      = (const float*)d_in[11];
  const float* b_att      = (const float*)d_in[12];
  const float* W_out      = (const float*)d_in[13];
  const float* b_out      = (const float*)d_in[14];
  const float* W_int      = (const float*)d_in[15];
  const float* b_int      = (const float*)d_in[16];
  float* out = (float*)d_out;

  char* ws = (char*)d_ws;
  const size_t ps_bytes = (size_t)BB * LL * DD * 2;   // 64 MB each
  float*    compound  = (float*)ws;                                   // 64 KB
  uint16_t* ps_a      = (uint16_t*)(ws + 65536);
  uint16_t* ps_b      = (uint16_t*)(ws + 65536 + ps_bytes);
  uint16_t* btab      = (uint16_t*)(ws + 65536 + 2 * ps_bytes);       // 90 KB
  float*    hvec_g    = (float*)(ws + 65536 + 2 * ps_bytes + 131072); // 64 KB
  // attn partials alias ps_a: ps_a's last reader is conv2; attn_part (sole
  // writer of these) is ordered after conv2.
  float*    pacc_part = (float*)ps_a;
  float*    msum_part = (float*)((char*)ps_a + (size_t)BB * ACH * 4 * 64 * 4);

  // gnn (+bfrag tail in blocks 0..2)
  gnn_kernel<<<BB, 256, 0, stream>>>(atoms, atoms_mask, adjacency, emb_fp,
                                     W_gnn, b_gnn, W_att, b_att,
                                     conv_k, btab, compound, hvec_g);
  // conv0 gathers emb_word[amino] in staging (gmode=1)
  conv_kernel<<<dim3(32, BB), 256, 0, stream>>>(ps_a, ps_b, btab, conv_b,
                                                amino, emb_word, 0, 1);
  conv_kernel<<<dim3(32, BB), 256, 0, stream>>>(ps_b, ps_a, btab, conv_b,
                                                amino, emb_word, 1, 0);
  conv_kernel<<<dim3(32, BB), 256, 0, stream>>>(ps_a, ps_b, btab, conv_b,
                                                amino, emb_word, 2, 0);
  attn_part_kernel<<<dim3(ACH, BB), 256, 0, stream>>>(ps_b, amino_mask, hvec_g,
                                                      W_att, b_att,
                                                      pacc_part, msum_part);
  attn_final_kernel<<<BB, 128, 0, stream>>>(compound, pacc_part, msum_part,
                                            W_out, b_out, W_int, b_int, out);
}